// Round 10
// baseline (184.246 us; speedup 1.0000x reference)
//
#include <hip/hip_runtime.h>

#define NN 8192
#define FIN 512
#define FOUT 256
#define JS 8
#define STRIP 1024
#define NSTEP 32

typedef _Float16 f16;
typedef __attribute__((ext_vector_type(2))) _Float16 f16x2;
typedef __attribute__((ext_vector_type(8))) _Float16 f16x8;
typedef __attribute__((ext_vector_type(4))) _Float16 f16x4;
typedef __attribute__((ext_vector_type(4))) float f32x4;
typedef __attribute__((ext_vector_type(16))) float f32x16;
typedef __attribute__((ext_vector_type(4))) int i32x4;
typedef unsigned long long u64;

__device__ __forceinline__ float lrelu(float x) { return fmaxf(x, 0.2f * x); }

// ---- prep W: f32 [FIN][FOUT] -> f16 hi/lo transposed [FOUT][FIN]
__global__ void k_prep_w(const float* __restrict__ W, f16* __restrict__ wth,
                         f16* __restrict__ wtl) {
  int id = blockIdx.x * 256 + threadIdx.x;
  int c = id >> 9, k = id & 511;
  float v = W[k * FOUT + c];
  f16 a = (f16)v;
  wth[c * FIN + k] = a;
  wtl[c * FIN + k] = (f16)(v - (float)a);
}

// ---- HETERO kernel: blocks [0,512) = gemm1 16-row tiles; blocks
// [512,2560) = adj->bitmask convert (wave = one row). Independent work
// overlaps across CUs instead of serializing.
// convert bit layout: word row*128+p*4+e, bit l <-> j = p*256 + e*64 + l
// (adjacent j = adjacent bits, for packed-f16 genP).
__launch_bounds__(256, 2)
__global__ void k_cvt_gemm(const int* __restrict__ adj, u64* __restrict__ maskG,
                           const float* __restrict__ h, const f16* __restrict__ wth,
                           const f16* __restrict__ wtl, const float* __restrict__ avec,
                           f16* __restrict__ whT16, float* __restrict__ wh1,
                           float* __restrict__ wh2) {
  int bid = blockIdx.x;
  int tid = threadIdx.x;
  __shared__ float tile[16][FOUT + 1];
  if (bid < NN / 16) {
    // ---------------- gemm1: Wh = h@W (split-f16), 16 rows x 256 cols
    int i0 = bid * 16;
    int w = tid >> 6, l = tid & 63, m = l & 15, g = l >> 4;
    f32x4 acc[4] = {};
#pragma unroll 1
    for (int k0 = 0; k0 < FIN; k0 += 32) {
      f16x8 ah, al, bh[4], bl[4];
      {
        int ro = (i0 + m) * FIN + k0 + 8 * g;
        f32x4 va = *(const f32x4*)(h + ro);
        f32x4 vb = *(const f32x4*)(h + ro + 4);
#pragma unroll
        for (int e = 0; e < 4; ++e) {
          f16 x = (f16)va[e];
          ah[e] = x;
          al[e] = (f16)(va[e] - (float)x);
          f16 y = (f16)vb[e];
          ah[4 + e] = y;
          al[4 + e] = (f16)(vb[e] - (float)y);
        }
      }
#pragma unroll
      for (int cf = 0; cf < 4; ++cf) {
        int co = (64 * w + 16 * cf + m) * FIN + k0 + 8 * g;
        bh[cf] = *(const f16x8*)(wth + co);
        bl[cf] = *(const f16x8*)(wtl + co);
      }
#pragma unroll
      for (int cf = 0; cf < 4; ++cf) {
        acc[cf] = __builtin_amdgcn_mfma_f32_16x16x32_f16(ah, bh[cf], acc[cf], 0, 0, 0);
        acc[cf] = __builtin_amdgcn_mfma_f32_16x16x32_f16(ah, bl[cf], acc[cf], 0, 0, 0);
        acc[cf] = __builtin_amdgcn_mfma_f32_16x16x32_f16(al, bh[cf], acc[cf], 0, 0, 0);
      }
    }
#pragma unroll
    for (int cf = 0; cf < 4; ++cf)
#pragma unroll
      for (int r = 0; r < 4; ++r)
        tile[4 * ((tid & 63) >> 4) + r][64 * (tid >> 6) + 16 * cf + (tid & 15)] = acc[cf][r];
    __syncthreads();
    {  // whT16 tiled write: thread = column c, 16 rows = 1 j16-group
      int c = tid;
      f16x8 vv[2];
#pragma unroll
      for (int r = 0; r < 16; ++r) vv[r >> 3][r & 7] = (f16)tile[r][c];
      size_t base = ((size_t)(i0 >> 4) * 256 + c) * 16;
      *(f16x8*)(whT16 + base) = vv[0];
      *(f16x8*)(whT16 + base + 8) = vv[1];
    }
    {  // Wh1/Wh2: 16 lanes per row (wave-internal shuffles)
      int r = tid >> 4, ls = tid & 15;
      float s1 = 0.f, s2 = 0.f;
      for (int c = ls; c < FOUT; c += 16) {
        float v = tile[r][c];
        s1 = fmaf(v, avec[c], s1);
        s2 = fmaf(v, avec[FOUT + c], s2);
      }
#pragma unroll
      for (int off = 1; off < 16; off <<= 1) {
        s1 += __shfl_xor(s1, off);
        s2 += __shfl_xor(s2, off);
      }
      if (ls == 0) {
        wh1[i0 + r] = s1;
        wh2[i0 + r] = s2;
      }
    }
  } else {
    // ---------------- convert: wave = one adj row, ballot packing
    int gw = (bid - NN / 16) * 4 + (tid >> 6);
    int l = tid & 63;
    const int* src = adj + (size_t)gw * NN + l;
    u64* dst = maskG + (size_t)gw * 128;
    int v[2][4];
#pragma unroll
    for (int e = 0; e < 4; ++e) {
      v[0][e] = __builtin_nontemporal_load(src + e * 64);
      v[1][e] = __builtin_nontemporal_load(src + 256 + e * 64);
    }
#pragma unroll 1
    for (int p = 0; p < 32; ++p) {
      int c0 = v[p & 1][0], c1 = v[p & 1][1], c2 = v[p & 1][2], c3 = v[p & 1][3];
      if (p + 2 < 32) {
#pragma unroll
        for (int e = 0; e < 4; ++e)
          v[p & 1][e] = __builtin_nontemporal_load(src + (p + 2) * 256 + e * 64);
      }
      u64 b0 = __ballot(c0 > 0);
      u64 b1 = __ballot(c1 > 0);
      u64 b2 = __ballot(c2 > 0);
      u64 b3 = __ballot(c3 > 0);
      if (l < 4) {
        u64 bb = (l == 0) ? b0 : (l == 1) ? b1 : (l == 2) ? b2 : b3;
        dst[p * 4 + l] = bb;
      }
    }
  }
}

// ---- global max of Wh2 + f16 factor tables. P = max(E1p*e2p, E1n*e2n)
// exactly equals exp(lrelu(w1+w2)-m) since exp is monotone and
// lrelu = max(s, 0.2s).
__global__ void k_maxprep(const float* __restrict__ wh1, const float* __restrict__ wh2,
                          f16* __restrict__ e1ph, f16* __restrict__ e1nh,
                          f16* __restrict__ e2ph, f16* __restrict__ e2nh) {
  int t = threadIdx.x;
  float mx = -1e30f;
  for (int i = t; i < NN; i += 256) mx = fmaxf(mx, wh2[i]);
#pragma unroll
  for (int off = 1; off < 64; off <<= 1) mx = fmaxf(mx, __shfl_xor(mx, off));
  __shared__ float sm[4];
  if ((t & 63) == 0) sm[t >> 6] = mx;
  __syncthreads();
  float M2 = fmaxf(fmaxf(sm[0], sm[1]), fmaxf(sm[2], sm[3]));
  const float L = 1.4426950408889634f;
  int i = blockIdx.x * 256 + t;
  float w1 = wh1[i], w2 = wh2[i];
  float m = lrelu(w1 + M2);
  e1ph[i] = (f16)exp2f((w1 - m) * L);
  e1nh[i] = (f16)exp2f((0.2f * w1 - m) * L);
  e2ph[i] = (f16)exp2f(w2 * L);
  e2nh[i] = (f16)exp2f(0.2f * w2 * L);
}

// ---- fused masked-softmax + PV, packed-f16 genP (exact max identity),
// B via LDS (dbuf, verified <=2-way-conflict XOR swizzle), masks in
// wave-private LDS. Wave = 32 rows x 256 cols x 1024-j strip; one
// barrier/step. acc[8] f32x16 = 128 AGPR. Grid 64rb x 8js.
__launch_bounds__(256, 2)
__global__ void k_attn(const u64* __restrict__ maskG, const f16* __restrict__ whT16,
                       const f16* __restrict__ e1ph, const f16* __restrict__ e1nh,
                       const f16* __restrict__ e2ph, const f16* __restrict__ e2nh,
                       f16* __restrict__ accP, float* __restrict__ zP) {
  int bx = blockIdx.x;
  int js = bx & (JS - 1), rb = bx >> 3;
  int i0b = rb * 128;
  int jbase = js * STRIP;
  int tid = threadIdx.x, w = tid >> 6, l = tid & 63;
  int lr = l & 31, hi = l >> 5;
  int row = i0b + w * 32 + lr;

  __shared__ u64 mrow[4][32][18];
  __shared__ __align__(16) char ldsB[2][16384];

  // stage this wave's 32 rows x 16 mask words (wave-private, in-order DS)
#pragma unroll
  for (int p = 0; p < 4; ++p) {
    int r = 8 * p + (l >> 3);
    const i32x4* src =
        (const i32x4*)(maskG + (size_t)(i0b + 32 * w + r) * 128 + js * 16) + (l & 7);
    *(i32x4*)(&mrow[w][r][(l & 7) * 2]) = *src;
  }

  f16 e1pa = e1ph[row], e1na = e1nh[row];
  f16x2 E1p2 = {e1pa, e1pa}, E1n2 = {e1na, e1na};
  const f16x2 ONE2 = {(f16)1.0f, (f16)1.0f};

  f32x16 acc[8] = {};
  float za = 0.f;

  const f16* bStrip = whT16 + (size_t)(jbase >> 4) * 4096;
  const f16* e2pb = e2ph + jbase;
  const f16* e2nb = e2nh + jbase;

  // staging map: granule g (16B) -> linear src g*8 f16; LDS slot XOR-swizzled
  int gidx[4], ldst[4];
#pragma unroll
  for (int r = 0; r < 4; ++r) {
    int g = r * 256 + tid;  // 0..1023 (two 16-j half-tiles)
    int kb = g >> 9, n = g & 511;
    int ns = n ^ ((n >> 3) & 3);
    gidx[r] = g * 8;
    ldst[r] = kb * 8192 + ns * 16;
  }
  // read base: granule n = (cf*32+lr)*2+hi; same-XOR folds to lane constant
  int nb = 2 * lr + hi;
  int rdbase = (nb * 16) ^ (((nb >> 3) & 3) << 4);

  f16x8 stg[4];
#pragma unroll
  for (int r = 0; r < 4; ++r) stg[r] = *(const f16x8*)(bStrip + gidx[r]);
#pragma unroll
  for (int r = 0; r < 4; ++r) *(f16x8*)(&ldsB[0][ldst[r]]) = stg[r];
  __syncthreads();

#pragma unroll 1
  for (int ch = 0; ch < 4; ++ch) {
    u64 wreg[4];
#pragma unroll
    for (int q = 0; q < 4; ++q) wreg[q] = mrow[w][lr][ch * 4 + q];
#pragma unroll 1
    for (int ts = 0; ts < 8; ++ts) {
      int t = ch * 8 + ts;
      int cur = t & 1;
      int jc = t * 32;
      // issue B(t+1) global loads (hide under genP + MFMA)
      if (t + 1 < NSTEP) {
        const f16* src = bStrip + (size_t)(t + 1) * 8192;
#pragma unroll
        for (int r = 0; r < 4; ++r) stg[r] = *(const f16x8*)(src + gidx[r]);
      }
      // packed genP: 16 P/lane as 8 f16x2 pairs; bit k of b32 <-> j = jc+k
      unsigned b32 = (unsigned)(wreg[ts >> 1] >> ((ts & 1) << 5));
      union {
        f16x2 p[4];
        f16x8 v;
      } A0, A1;
#pragma unroll
      for (int pp = 0; pp < 4; ++pp) {
        int fo = jc + hi * 8 + pp * 2;
        f16x2 ep0 = *(const f16x2*)(e2pb + fo);
        f16x2 en0 = *(const f16x2*)(e2nb + fo);
        f16x2 m0 = __builtin_elementwise_max(E1p2 * ep0, E1n2 * en0);
        unsigned bb0 = (b32 >> (hi * 8 + pp * 2)) & 3u;
        unsigned msk0 = (bb0 & 1u ? 0xFFFFu : 0u) | (bb0 & 2u ? 0xFFFF0000u : 0u);
        m0 = __builtin_bit_cast(f16x2, __builtin_bit_cast(unsigned, m0) & msk0);
        za = __builtin_amdgcn_fdot2(m0, ONE2, za, false);
        A0.p[pp] = m0;
        f16x2 ep1 = *(const f16x2*)(e2pb + fo + 16);
        f16x2 en1 = *(const f16x2*)(e2nb + fo + 16);
        f16x2 m1 = __builtin_elementwise_max(E1p2 * ep1, E1n2 * en1);
        unsigned bb1 = (b32 >> (16 + hi * 8 + pp * 2)) & 3u;
        unsigned msk1 = (bb1 & 1u ? 0xFFFFu : 0u) | (bb1 & 2u ? 0xFFFF0000u : 0u);
        m1 = __builtin_bit_cast(f16x2, __builtin_bit_cast(unsigned, m1) & msk1);
        za = __builtin_amdgcn_fdot2(m1, ONE2, za, false);
        A1.p[pp] = m1;
      }
      // MFMA from LDS (conflict-checked swizzle)
#pragma unroll
      for (int cf = 0; cf < 8; ++cf) {
        f16x8 bf0 = *(const f16x8*)(&ldsB[cur][cf * 1024 + rdbase]);
        acc[cf] = __builtin_amdgcn_mfma_f32_32x32x16_f16(A0.v, bf0, acc[cf], 0, 0, 0);
      }
#pragma unroll
      for (int cf = 0; cf < 8; ++cf) {
        f16x8 bf1 = *(const f16x8*)(&ldsB[cur][8192 + cf * 1024 + rdbase]);
        acc[cf] = __builtin_amdgcn_mfma_f32_32x32x16_f16(A1.v, bf1, acc[cf], 0, 0, 0);
      }
      if (t + 1 < NSTEP) {
#pragma unroll
        for (int r = 0; r < 4; ++r) *(f16x8*)(&ldsB[cur ^ 1][ldst[r]]) = stg[r];
        __syncthreads();
      }
    }
  }

  // Z: hi=0/1 lanes hold complementary j-slots of row
  za += __shfl_xor(za, 32);
  if (hi == 0) zP[(size_t)js * NN + row] = za;

  // partial accumulator out, f16 NT. C/D: col=lane&31, row=(r&3)+8*(r>>2)+4*hi
  f16* ap = accP + (size_t)js * NN * FOUT;
#pragma unroll
  for (int c = 0; c < 8; ++c)
#pragma unroll
    for (int r = 0; r < 16; ++r) {
      int grow = i0b + 32 * w + (r & 3) + 8 * (r >> 2) + 4 * hi;
      int gcol = c * 32 + lr;
      __builtin_nontemporal_store((f16)acc[c][r], ap + (size_t)grow * FOUT + gcol);
    }
}

// ---- combine JS f16 partials, divide by Z, elu
__global__ void k_combine(const f16* __restrict__ accP, const float* __restrict__ zP,
                          float* __restrict__ out) {
  int id = blockIdx.x * 256 + threadIdx.x;
  size_t idx = (size_t)id * 4;
  int row = (int)(idx >> 8);
  f32x4 s = {};
#pragma unroll
  for (int p = 0; p < JS; ++p) {
    f16x4 v = *(const f16x4*)(accP + (size_t)p * NN * FOUT + idx);
#pragma unroll
    for (int i = 0; i < 4; ++i) s[i] += (float)v[i];
  }
  float z = 0.f;
#pragma unroll
  for (int p = 0; p < JS; ++p) z += zP[(size_t)p * NN + row];
  float inv = (z > 0.f) ? 1.f / z : 0.f;
  f32x4 o;
#pragma unroll
  for (int i = 0; i < 4; ++i) {
    float x = s[i] * inv;
    o[i] = (x > 0.f) ? x : expm1f(x);
  }
  *(f32x4*)(out + idx) = o;
}

extern "C" void kernel_launch(void* const* d_in, const int* in_sizes, int n_in,
                              void* d_out, int out_size, void* d_ws, size_t ws_size,
                              hipStream_t stream) {
  const float* h = (const float*)d_in[0];
  const int* adj = (const int*)d_in[1];
  const float* W = (const float*)d_in[2];
  const float* a = (const float*)d_in[3];
  (void)in_sizes; (void)n_in; (void)out_size; (void)ws_size;

  char* ws = (char*)d_ws;
  size_t off = 0;
  auto alloc = [&](size_t bytes) {
    void* p = ws + off;
    off = (off + bytes + 255) & ~(size_t)255;
    return p;
  };
  f16* accP = (f16*)alloc((size_t)JS * NN * FOUT * 2);  // 32 MB
  u64* maskG = (u64*)alloc((size_t)NN * 128 * 8);       // 8 MB
  f16* whT16 = (f16*)alloc((size_t)FOUT * NN * 2);      // 4 MB
  f16* wth = (f16*)alloc((size_t)FOUT * FIN * 2);
  f16* wtl = (f16*)alloc((size_t)FOUT * FIN * 2);
  float* wh1 = (float*)alloc((size_t)NN * 4);
  float* wh2 = (float*)alloc((size_t)NN * 4);
  f16* e1ph = (f16*)alloc((size_t)NN * 2);
  f16* e1nh = (f16*)alloc((size_t)NN * 2);
  f16* e2ph = (f16*)alloc((size_t)NN * 2);
  f16* e2nh = (f16*)alloc((size_t)NN * 2);
  float* zP = (float*)alloc((size_t)JS * NN * 4);

  k_prep_w<<<FIN * FOUT / 256, 256, 0, stream>>>(W, wth, wtl);
  k_cvt_gemm<<<NN / 16 + NN / 4, 256, 0, stream>>>(adj, maskG, h, wth, wtl, a,
                                                   whT16, wh1, wh2);
  k_maxprep<<<NN / 256, 256, 0, stream>>>(wh1, wh2, e1ph, e1nh, e2ph, e2nh);
  k_attn<<<(NN / 128) * JS, 256, 0, stream>>>(maskG, whT16, e1ph, e1nh, e2ph, e2nh,
                                              accP, zP);
  k_combine<<<NN * FOUT / 1024, 256, 0, stream>>>(accP, zP, (float*)d_out);
}